// Round 3
// baseline (518.960 us; speedup 1.0000x reference)
//
#include <hip/hip_runtime.h>

typedef float f32x2 __attribute__((ext_vector_type(2)));
typedef float f32x4 __attribute__((ext_vector_type(4)));

#define LOG2E 1.44269504088896340736f

static __device__ __forceinline__ float rcp_fast(float x) { return __builtin_amdgcn_rcpf(x); }

static __device__ __forceinline__ f32x2 mk2(float a, float b) { f32x2 v; v[0] = a; v[1] = b; return v; }

static __device__ __forceinline__ float sigmoid_fast(float x) {
    // 1/(1+exp(-x)); exp2 overflow -> inf -> rcp -> 0 (correct limit), no NaN
    return rcp_fast(1.0f + __builtin_amdgcn_exp2f(-LOG2E * x));
}

static __device__ __forceinline__ float tanh_fast(float x) {
    float a = __builtin_fabsf(x);
    float t = __builtin_amdgcn_exp2f(-2.0f * LOG2E * a);
    float r = (1.0f - t) * rcp_fast(1.0f + t);
    return __builtin_copysignf(r, x);
}

// exchange with lane^16 (pairs the two k-halves of the same batch/hidden j)
static __device__ __forceinline__ float xor16(float v) {
    return __int_as_float(__builtin_amdgcn_ds_swizzle(__float_as_int(v), 0x401F));
}

// 8 contiguous floats -> 4 f32x2 (2x ds_read_b128 / global b128)
static __device__ __forceinline__ void load_pairs8(const float* p, f32x2* dst) {
    const f32x4* q4 = (const f32x4*)p;
    f32x4 a = q4[0], b = q4[1];
    dst[0] = __builtin_shufflevector(a, a, 0, 1);
    dst[1] = __builtin_shufflevector(a, a, 2, 3);
    dst[2] = __builtin_shufflevector(b, b, 0, 1);
    dst[3] = __builtin_shufflevector(b, b, 2, 3);
}

// 16 contiguous floats -> 8 f32x2 (preamble only)
static __device__ __forceinline__ void load_pairs16(const float* p, f32x2* dst) {
    load_pairs8(p, dst);
    load_pairs8(p + 8, dst + 4);
}

// K-SPLIT decomposition: 32 lanes per batch element, 2 batches per wave.
// Lane (g = lane>>5 batch, half = (lane>>4)&1 k-half, j = lane&15 hidden idx)
// holds the k-half slice (8 of 16 k values) of the weight rows for hidden j.
// Partial dot products are reduced across the two halves with ds_swizzle
// xor-16 (7 per step: 2 LN stats, 4 gates, 1 W_out). Both halves then compute
// identical c/h/state (commutative adds -> bitwise identical).
// Wave count = B/2 = 4096 = 4 waves/SIMD (vs 2 before): latency hiding comes
// from hardware TLP, not compiler scheduling. Weights sliced in half keep the
// per-wave VGPR demand under the 128 needed for 4-wave residency.
__global__ __launch_bounds__(64, 4) void vm_kernel(
    const float* __restrict__ init_state,  // (B,1,12)
    const float* __restrict__ commands,    // (B,T,4)
    const float* __restrict__ ln_g,        // (16)
    const float* __restrict__ ln_b,        // (16)
    const float* __restrict__ W_in,        // (16,16)
    const float* __restrict__ b_in,        // (16)
    const float* __restrict__ W_ih,        // (64,16)
    const float* __restrict__ W_hh,        // (64,16)
    const float* __restrict__ b_ih,        // (64)
    const float* __restrict__ b_hh,        // (64)
    const float* __restrict__ W_out,       // (12,16)
    const float* __restrict__ b_out,       // (12)
    float* __restrict__ out,               // (B,T,12)
    int B, int T)
{
    const int lane = threadIdx.x;
    const int j = lane & 15;
    const int half = (lane >> 4) & 1;
    const int g = lane >> 5;
    const int b = blockIdx.x * 2 + g;
    const int kb = half * 8;              // this lane's k-slice start
    const bool hf0 = (half == 0);
    const bool is_state = (j < 12);

    // stride 24 floats: write banks 2-way max, b128 broadcast reads 2-way max.
    __shared__ __align__(16) float shx[2][24];
    __shared__ __align__(16) float shh[2][24];

    // ---- preamble: W_ih full rows transient; W_hh/W_out k-half slices ----
    f32x2 Wih[4][8], Wh[4][4];
#pragma unroll
    for (int q = 0; q < 4; ++q) {
        load_pairs16(W_ih + (q * 16 + j) * 16, Wih[q]);
        load_pairs8(W_hh + (q * 16 + j) * 16 + kb, Wh[q]);
    }

    // W_eff = W_ih @ W_in (k-half slice of row q*16+j), plus b_in fold
    f32x2 Wgx[4][4];
    float binacc[4];
#pragma unroll
    for (int q = 0; q < 4; ++q) {
        binacc[q] = 0.0f;
#pragma unroll
        for (int k2 = 0; k2 < 4; ++k2) Wgx[q][k2] = mk2(0.0f, 0.0f);
    }
#pragma unroll
    for (int m = 0; m < 16; ++m) {
        f32x2 wm[4];
        load_pairs8(W_in + m * 16 + kb, wm);   // k-half slice of W_in row m
        float bm = b_in[m];
#pragma unroll
        for (int q = 0; q < 4; ++q) {
            float wim = Wih[q][m >> 1][m & 1]; // full-row element (both halves)
            f32x2 w2 = mk2(wim, wim);
#pragma unroll
            for (int k2 = 0; k2 < 4; ++k2) Wgx[q][k2] += w2 * wm[k2];
            binacc[q] += wim * bm;             // full sum (identical both halves)
        }
    }
    // fold LN gamma/beta; sg/cst need FULL-k sums -> preamble xor16 reduce
    float sg[4], cst[4];
    {
        f32x2 gg2[4], bt2[4];
        load_pairs8(ln_g + kb, gg2);
        load_pairs8(ln_b + kb, bt2);
#pragma unroll
        for (int q = 0; q < 4; ++q) {
            f32x2 ss = mk2(0.0f, 0.0f), cc = mk2(0.0f, 0.0f);
#pragma unroll
            for (int k2 = 0; k2 < 4; ++k2) {
                cc += Wgx[q][k2] * bt2[k2];    // beta applied to pre-gamma W_eff
                Wgx[q][k2] *= gg2[k2];
                ss += Wgx[q][k2];
            }
            float sp = ss[0] + ss[1];
            float cp = cc[0] + cc[1];
            sg[q] = sp + xor16(sp);
            cst[q] = (cp + xor16(cp)) + binacc[q]
                   + b_ih[q * 16 + j] + b_hh[q * 16 + j];
        }
    }

    f32x2 Wo[4];
    float bo = 0.0f;
#pragma unroll
    for (int k2 = 0; k2 < 4; ++k2) Wo[k2] = mk2(0.0f, 0.0f);
    if (is_state) {
        load_pairs8(W_out + j * 16 + kb, Wo);
        bo = b_out[j];
    }

    // ---- recurrent state (replicated across the two halves) ----
    float st = is_state ? init_state[b * 12 + j] : 0.0f;
    float c = 0.0f;
    f32x2 hp[4];
#pragma unroll
    for (int k2 = 0; k2 < 4; ++k2) hp[k2] = mk2(0.0f, 0.0f);

    const float* cmd_ptr = commands + (size_t)b * T * 4 + (j >= 12 ? j - 12 : 0);
    float* out_ptr = out + (size_t)b * T * 12 + j;
    const bool do_cmd = hf0 && (j >= 12);

    // sincos partner: pairs (1,2),(3,4),(5,6)
    int pj = j;
    if (j >= 1 && j <= 6) pj = ((j - 1) ^ 1) + 1;
    const float* ppart = &shx[g][pj];
    const bool donorm = (j >= 1 && j <= 6);

    // ---- prologue: stage x0 = raw init state || cmd0 (no initial renorm) ----
    float cmd0 = do_cmd ? cmd_ptr[0] : 0.0f;
    if (hf0) shx[g][j] = is_state ? st : cmd0;
    f32x2 xp[4];
    load_pairs8(&shx[g][kb], xp);

    float mu, inv;
    {
        f32x2 s2 = (xp[0] + xp[1]) + (xp[2] + xp[3]);
        float sp = s2[0] + s2[1];
        f32x2 qq = xp[0] * xp[0];
#pragma unroll
        for (int k2 = 1; k2 < 4; ++k2) qq += xp[k2] * xp[k2];
        float qp = qq[0] + qq[1];
        float sum = sp + xor16(sp);
        float sumsq = qp + xor16(qp);
        mu = sum * 0.0625f;
        float var = sumsq * 0.0625f - mu * mu;
        inv = __builtin_amdgcn_rsqf(var + 1e-5f);
    }

    // 2-deep command prefetch
    float cmdS = do_cmd ? cmd_ptr[(size_t)(T > 1 ? 1 : 0) * 4] : 0.0f;
    float cmdN = do_cmd ? cmd_ptr[(size_t)(T > 2 ? 2 : 0) * 4] : 0.0f;

    for (int t = 0; t < T; ++t) {
        // ---- partial gate dots over this lane's k-half ----
        f32x2 a0 = Wgx[0][0] * xp[0], a1 = Wgx[1][0] * xp[0];
        f32x2 a2 = Wgx[2][0] * xp[0], a3 = Wgx[3][0] * xp[0];
        f32x2 h0 = Wh[0][0] * hp[0], h1 = Wh[1][0] * hp[0];
        f32x2 h2 = Wh[2][0] * hp[0], h3 = Wh[3][0] * hp[0];
#pragma unroll
        for (int k2 = 1; k2 < 4; ++k2) {
            a0 += Wgx[0][k2] * xp[k2]; a1 += Wgx[1][k2] * xp[k2];
            a2 += Wgx[2][k2] * xp[k2]; a3 += Wgx[3][k2] * xp[k2];
            h0 += Wh[0][k2] * hp[k2];  h1 += Wh[1][k2] * hp[k2];
            h2 += Wh[2][k2] * hp[k2];  h3 += Wh[3][k2] * hp[k2];
        }
        // apply inv to own partial ((ax0+ax1)*inv == ax0*inv+ax1*inv), add h part
        float p0 = __builtin_fmaf(a0[0] + a0[1], inv, h0[0] + h0[1]);
        float p1 = __builtin_fmaf(a1[0] + a1[1], inv, h1[0] + h1[1]);
        float p2 = __builtin_fmaf(a2[0] + a2[1], inv, h2[0] + h2[1]);
        float p3 = __builtin_fmaf(a3[0] + a3[1], inv, h3[0] + h3[1]);
        // cross-half reduce (commutative -> identical on both halves)
        float r0 = p0 + xor16(p0);
        float r1 = p1 + xor16(p1);
        float r2 = p2 + xor16(p2);
        float r3 = p3 + xor16(p3);
        float nmi = -mu * inv;
        float gi = r0 + __builtin_fmaf(nmi, sg[0], cst[0]);
        float gf = r1 + __builtin_fmaf(nmi, sg[1], cst[1]);
        float gG = r2 + __builtin_fmaf(nmi, sg[2], cst[2]);
        float go = r3 + __builtin_fmaf(nmi, sg[3], cst[3]);

        float iv = sigmoid_fast(gi);
        float fv = sigmoid_fast(gf);
        float gv = tanh_fast(gG);
        float ov = sigmoid_fast(go);
        c = fv * c + iv * gv;
        float hv = ov * tanh_fast(c);

        // ---- distribute h (write once per j, read k-half fragments) ----
        if (hf0) shh[g][j] = hv;
        load_pairs8(&shh[g][kb], hp);

        // ---- W_out partial + cross-half reduce ----
        f32x2 o2 = Wo[0] * hp[0];
#pragma unroll
        for (int k2 = 1; k2 < 4; ++k2) o2 += Wo[k2] * hp[k2];
        float po = o2[0] + o2[1];
        float o = po + xor16(po);
        float st_raw = st + o + bo;            // j>=12: dead value

        // ---- stage next x (raw state + cmd), read fragments ----
        if (hf0) shx[g][j] = is_state ? st_raw : cmdS;
        float pv = *ppart;                     // partner raw value
        load_pairs8(&shx[g][kb], xp);

        // own sincos renorm for the register copy of st
        float nrm = __builtin_amdgcn_sqrtf(st_raw * st_raw + pv * pv) + 1e-8f;
        float stn = st_raw * rcp_fast(nrm);
        st = donorm ? stn : st_raw;
        if (hf0 && is_state) out_ptr[0] = st;
        out_ptr += 12;

        // renorm pairs (1,2),(3,4),(5,6) — all inside the half-0 fragment
        if (hf0) {
            {
                float a = xp[0][1], bq = xp[1][0];
                float r = rcp_fast(__builtin_amdgcn_sqrtf(a * a + bq * bq) + 1e-8f);
                xp[0][1] = a * r; xp[1][0] = bq * r;
            }
            {
                float a = xp[1][1], bq = xp[2][0];
                float r = rcp_fast(__builtin_amdgcn_sqrtf(a * a + bq * bq) + 1e-8f);
                xp[1][1] = a * r; xp[2][0] = bq * r;
            }
            {
                float a = xp[2][1], bq = xp[3][0];
                float r = rcp_fast(__builtin_amdgcn_sqrtf(a * a + bq * bq) + 1e-8f);
                xp[2][1] = a * r; xp[3][0] = bq * r;
            }
        }

        // LN stats for next step (partial + cross-half reduce)
        {
            f32x2 s2 = (xp[0] + xp[1]) + (xp[2] + xp[3]);
            float sp = s2[0] + s2[1];
            f32x2 qq = xp[0] * xp[0];
#pragma unroll
            for (int k2 = 1; k2 < 4; ++k2) qq += xp[k2] * xp[k2];
            float qp = qq[0] + qq[1];
            float sum = sp + xor16(sp);
            float sumsq = qp + xor16(qp);
            mu = sum * 0.0625f;
            float var = sumsq * 0.0625f - mu * mu;
            inv = __builtin_amdgcn_rsqf(var + 1e-5f);
        }

        // rotate 2-deep cmd prefetch
        cmdS = cmdN;
        int tn = t + 3;
        if (tn > T - 1) tn = T - 1;
        if (do_cmd) cmdN = cmd_ptr[(size_t)tn * 4];
    }
}

extern "C" void kernel_launch(void* const* d_in, const int* in_sizes, int n_in,
                              void* d_out, int out_size, void* d_ws, size_t ws_size,
                              hipStream_t stream) {
    const float* init_state = (const float*)d_in[0];
    const float* commands   = (const float*)d_in[1];
    const float* ln_g       = (const float*)d_in[2];
    const float* ln_b       = (const float*)d_in[3];
    const float* W_in       = (const float*)d_in[4];
    const float* b_in       = (const float*)d_in[5];
    const float* W_ih       = (const float*)d_in[6];
    const float* W_hh       = (const float*)d_in[7];
    const float* b_ih       = (const float*)d_in[8];
    const float* b_hh       = (const float*)d_in[9];
    const float* W_out      = (const float*)d_in[10];
    const float* b_out      = (const float*)d_in[11];

    int B = in_sizes[0] / 12;           // 8192
    int T = in_sizes[1] / (B * 4);      // 256

    int blocks = B / 2;                 // 2 batch elements per 64-thread wave
    vm_kernel<<<blocks, 64, 0, stream>>>(init_state, commands, ln_g, ln_b,
                                         W_in, b_in, W_ih, W_hh, b_ih, b_hh,
                                         W_out, b_out, (float*)d_out, B, T);
}

// Round 5
// 393.092 us; speedup vs baseline: 1.3202x; 1.3202x over previous
//
#include <hip/hip_runtime.h>

typedef float f32x2 __attribute__((ext_vector_type(2)));
typedef float f32x4 __attribute__((ext_vector_type(4)));
typedef _Float16 h16x2 __attribute__((ext_vector_type(2)));
typedef __fp16 fp16x2_raw __attribute__((ext_vector_type(2)));

#define LOG2E 1.44269504088896340736f

static __device__ __forceinline__ float rcp_fast(float x) { return __builtin_amdgcn_rcpf(x); }

static __device__ __forceinline__ f32x2 mk2(float a, float b) { f32x2 v; v[0] = a; v[1] = b; return v; }

static __device__ __forceinline__ float sigmoid_fast(float x) {
    // 1/(1+exp(-x)); exp2 overflow -> inf -> rcp -> 0 (correct limit), no NaN
    return rcp_fast(1.0f + __builtin_amdgcn_exp2f(-LOG2E * x));
}

static __device__ __forceinline__ float tanh_fast(float x) {
    float a = __builtin_fabsf(x);
    float t = __builtin_amdgcn_exp2f(-2.0f * LOG2E * a);
    float r = (1.0f - t) * rcp_fast(1.0f + t);
    return __builtin_copysignf(r, x);
}

// v_dot2_f32_f16: c += a[0]*b[0] + a[1]*b[1] (f32 accumulate)
static __device__ __forceinline__ float fdot2(h16x2 a, h16x2 b, float c) {
#if __has_builtin(__builtin_amdgcn_fdot2)
    return __builtin_amdgcn_fdot2(a, b, c, false);
#else
    return c + (float)(a[0]) * (float)(b[0]) + (float)(a[1]) * (float)(b[1]);
#endif
}

// v_cvt_pkrtz_f16_f32 returns an __fp16 vector; bit-cast to _Float16 vector
static __device__ __forceinline__ h16x2 pk(float a, float b) {
    fp16x2_raw r = __builtin_amdgcn_cvt_pkrtz(a, b);
    return __builtin_bit_cast(h16x2, r);
}

// 16 contiguous floats -> 8 f32x2 (preamble only)
static __device__ __forceinline__ void load_pairs16(const float* p, f32x2* dst) {
    const f32x4* q4 = (const f32x4*)p;
    f32x4 a = q4[0], b = q4[1], c = q4[2], d = q4[3];
    dst[0] = __builtin_shufflevector(a, a, 0, 1);
    dst[1] = __builtin_shufflevector(a, a, 2, 3);
    dst[2] = __builtin_shufflevector(b, b, 0, 1);
    dst[3] = __builtin_shufflevector(b, b, 2, 3);
    dst[4] = __builtin_shufflevector(c, c, 0, 1);
    dst[5] = __builtin_shufflevector(c, c, 2, 3);
    dst[6] = __builtin_shufflevector(d, d, 0, 1);
    dst[7] = __builtin_shufflevector(d, d, 2, 3);
}

// REGISTER-ONLY broadcast design: 16 lanes per batch, 4 batches per wave
// (2048 waves = 2/SIMD). No LDS arrays: the per-step 16-wide broadcasts
// (h, x) are ds_bpermute all-gathers from registers -- 16 independent
// bpermutes = ~one LDS latency, no write->read round-trip. Weights are f16
// pairs consumed by v_dot2_f32_f16 (f32 accumulate): halves both register
// demand (~72 weight VGPRs) and dot issue count, so everything stays
// register-resident under __launch_bounds__(64,2) (256 VGPR budget).
__global__ __launch_bounds__(64, 2) void vm_kernel(
    const float* __restrict__ init_state,  // (B,1,12)
    const float* __restrict__ commands,    // (B,T,4)
    const float* __restrict__ ln_g,        // (16)
    const float* __restrict__ ln_b,        // (16)
    const float* __restrict__ W_in,        // (16,16)
    const float* __restrict__ b_in,        // (16)
    const float* __restrict__ W_ih,        // (64,16)
    const float* __restrict__ W_hh,        // (64,16)
    const float* __restrict__ b_ih,        // (64)
    const float* __restrict__ b_hh,        // (64)
    const float* __restrict__ W_out,       // (12,16)
    const float* __restrict__ b_out,       // (12)
    float* __restrict__ out,               // (B,T,12)
    int B, int T)
{
    const int lane = threadIdx.x;
    const int j = lane & 15;
    const int g = lane >> 4;
    const int b = blockIdx.x * 4 + g;
    const int gbase = (lane & 48) << 2;     // byte addr of own group's lane 0
    const bool is_state = (j < 12);

    // ---- preamble (f32 fold, identical math to verified R1) ----
    f32x2 Wih[4][8], Wh32[4][8];
#pragma unroll
    for (int q = 0; q < 4; ++q) {
        load_pairs16(W_ih + (q * 16 + j) * 16, Wih[q]);
        load_pairs16(W_hh + (q * 16 + j) * 16, Wh32[q]);
    }

    // W_eff = W_ih @ W_in (row q*16+j), plus b_in fold
    f32x2 Wgx[4][8];
    float binacc[4];
#pragma unroll
    for (int q = 0; q < 4; ++q) {
        binacc[q] = 0.0f;
#pragma unroll
        for (int k2 = 0; k2 < 8; ++k2) Wgx[q][k2] = mk2(0.0f, 0.0f);
    }
#pragma unroll
    for (int m = 0; m < 16; ++m) {
        f32x2 wm[8];
        load_pairs16(W_in + m * 16, wm);    // uniform address -> scalar loads
        float bm = b_in[m];
#pragma unroll
        for (int q = 0; q < 4; ++q) {
            float wim = Wih[q][m >> 1][m & 1];
            f32x2 w2 = mk2(wim, wim);
#pragma unroll
            for (int k2 = 0; k2 < 8; ++k2) Wgx[q][k2] += w2 * wm[k2];
            binacc[q] += wim * bm;
        }
    }
    // fold LN gamma/beta: gate = dot(Wgx,x)*inv - mu*inv*sg + cst + dot(Wh,h)
    float sg[4], cst[4];
    {
        f32x2 gg2[8], bt2[8];
        load_pairs16(ln_g, gg2);
        load_pairs16(ln_b, bt2);
#pragma unroll
        for (int q = 0; q < 4; ++q) {
            f32x2 ss = mk2(0.0f, 0.0f), cc = mk2(0.0f, 0.0f);
#pragma unroll
            for (int k2 = 0; k2 < 8; ++k2) {
                cc += Wgx[q][k2] * bt2[k2];  // beta applied to pre-gamma W_eff
                Wgx[q][k2] *= gg2[k2];
                ss += Wgx[q][k2];
            }
            sg[q]  = ss[0] + ss[1];
            cst[q] = cc[0] + cc[1] + binacc[q] + b_ih[q * 16 + j] + b_hh[q * 16 + j];
        }
    }

    // ---- convert weights to f16 pairs (register-resident working set) ----
    h16x2 WgxH[4][8], WhH[4][8];
#pragma unroll
    for (int q = 0; q < 4; ++q)
#pragma unroll
        for (int k2 = 0; k2 < 8; ++k2) {
            WgxH[q][k2] = pk(Wgx[q][k2][0], Wgx[q][k2][1]);
            WhH[q][k2]  = pk(Wh32[q][k2][0], Wh32[q][k2][1]);
        }

    h16x2 WoH[8];
    float bo = 0.0f;
#pragma unroll
    for (int k2 = 0; k2 < 8; ++k2) WoH[k2] = pk(0.0f, 0.0f);
    if (is_state) {
        f32x2 wo32[8];
        load_pairs16(W_out + j * 16, wo32);
#pragma unroll
        for (int k2 = 0; k2 < 8; ++k2) WoH[k2] = pk(wo32[k2][0], wo32[k2][1]);
        bo = b_out[j];
    }

    const h16x2 one2 = pk(1.0f, 1.0f);

    // ---- recurrent state ----
    float st = is_state ? init_state[b * 12 + j] : 0.0f;
    float c = 0.0f;
    h16x2 hpk[8];
#pragma unroll
    for (int k2 = 0; k2 < 8; ++k2) hpk[k2] = pk(0.0f, 0.0f);

    const float* cmd_ptr = commands + (size_t)b * T * 4 + (j >= 12 ? j - 12 : 0);
    float* out_ptr = out + (size_t)b * T * 12 + j;
    const bool do_cmd = (j >= 12);

    // sincos partner: pairs (1,2),(3,4),(5,6)
    int pj = j;
    if (j >= 1 && j <= 6) pj = ((j - 1) ^ 1) + 1;
    const int paddr = ((lane & 48) | pj) << 2;
    const bool donorm = (j >= 1 && j <= 6);

    // all-gather the own-group value v into 16 registers via bpermute
#define GATHER16(v, dst)                                                      \
    do {                                                                      \
        int _s = __float_as_int(v);                                           \
        _Pragma("unroll")                                                     \
        for (int _i = 0; _i < 16; ++_i)                                       \
            dst[_i] = __int_as_float(                                         \
                __builtin_amdgcn_ds_bpermute(gbase + (_i << 2), _s));         \
    } while (0)

    // ---- prologue: x0 = raw init state || cmd0 (no initial renorm) ----
    float cmd0 = do_cmd ? cmd_ptr[0] : 0.0f;
    h16x2 xpk[8];
    float mu, inv;
    {
        float xv = is_state ? st : cmd0;
        float xg[16];
        GATHER16(xv, xg);
#pragma unroll
        for (int i = 0; i < 8; ++i) xpk[i] = pk(xg[2 * i], xg[2 * i + 1]);
        float s0 = 0.0f, s1 = 0.0f, q0 = 0.0f, q1 = 0.0f;
#pragma unroll
        for (int i = 0; i < 4; ++i) {
            s0 = fdot2(xpk[i], one2, s0);
            s1 = fdot2(xpk[i + 4], one2, s1);
            q0 = fdot2(xpk[i], xpk[i], q0);
            q1 = fdot2(xpk[i + 4], xpk[i + 4], q1);
        }
        mu = (s0 + s1) * 0.0625f;
        float var = (q0 + q1) * 0.0625f - mu * mu;
        inv = __builtin_amdgcn_rsqf(var + 1e-5f);
    }

    // 2-deep command prefetch
    float cmdS = do_cmd ? cmd_ptr[(size_t)(T > 1 ? 1 : 0) * 4] : 0.0f;
    float cmdN = do_cmd ? cmd_ptr[(size_t)(T > 2 ? 2 : 0) * 4] : 0.0f;

    for (int t = 0; t < T; ++t) {
        // ---- gates: dot2 over f16 pairs, two chains per gate for ILP ----
        float gx[4], gh[4];
#pragma unroll
        for (int q = 0; q < 4; ++q) {
            float a0 = 0.0f, a1 = 0.0f, h0 = 0.0f, h1 = 0.0f;
#pragma unroll
            for (int k = 0; k < 4; ++k) {
                a0 = fdot2(WgxH[q][k], xpk[k], a0);
                a1 = fdot2(WgxH[q][k + 4], xpk[k + 4], a1);
                h0 = fdot2(WhH[q][k], hpk[k], h0);
                h1 = fdot2(WhH[q][k + 4], hpk[k + 4], h1);
            }
            gx[q] = a0 + a1;
            gh[q] = h0 + h1;
        }
        float nmi = -mu * inv;
        float gi = __builtin_fmaf(gx[0], inv, __builtin_fmaf(nmi, sg[0], cst[0] + gh[0]));
        float gf = __builtin_fmaf(gx[1], inv, __builtin_fmaf(nmi, sg[1], cst[1] + gh[1]));
        float gG = __builtin_fmaf(gx[2], inv, __builtin_fmaf(nmi, sg[2], cst[2] + gh[2]));
        float go = __builtin_fmaf(gx[3], inv, __builtin_fmaf(nmi, sg[3], cst[3] + gh[3]));

        float iv = sigmoid_fast(gi);
        float fv = sigmoid_fast(gf);
        float gv = tanh_fast(gG);
        float ov = sigmoid_fast(go);
        c = fv * c + iv * gv;
        float hv = ov * tanh_fast(c);

        // ---- h all-gather (registers only) + pack for dot2 ----
        {
            float hg[16];
            GATHER16(hv, hg);
#pragma unroll
            for (int i = 0; i < 8; ++i) hpk[i] = pk(hg[2 * i], hg[2 * i + 1]);
        }

        // ---- W_out dot + state update ----
        float o0 = 0.0f, o1 = 0.0f;
#pragma unroll
        for (int k = 0; k < 4; ++k) {
            o0 = fdot2(WoH[k], hpk[k], o0);
            o1 = fdot2(WoH[k + 4], hpk[k + 4], o1);
        }
        float st_raw = st + (o0 + o1) + bo;     // j>=12: stays 0 (WoH=0,bo=0)

        // ---- sincos renorm at source (partner raw via 1 bpermute) ----
        float pv = __int_as_float(
            __builtin_amdgcn_ds_bpermute(paddr, __float_as_int(st_raw)));
        float nrm = __builtin_amdgcn_sqrtf(st_raw * st_raw + pv * pv) + 1e-8f;
        float stn = st_raw * rcp_fast(nrm);
        st = donorm ? stn : st_raw;
        if (is_state) out_ptr[0] = st;
        out_ptr += 12;

        // ---- x all-gather of NORMED state / cmd, pack, LN stats ----
        {
            float xv = is_state ? st : cmdS;
            float xg[16];
            GATHER16(xv, xg);
#pragma unroll
            for (int i = 0; i < 8; ++i) xpk[i] = pk(xg[2 * i], xg[2 * i + 1]);
        }
        float s0 = 0.0f, s1 = 0.0f, q0 = 0.0f, q1 = 0.0f;
#pragma unroll
        for (int i = 0; i < 4; ++i) {
            s0 = fdot2(xpk[i], one2, s0);
            s1 = fdot2(xpk[i + 4], one2, s1);
            q0 = fdot2(xpk[i], xpk[i], q0);
            q1 = fdot2(xpk[i + 4], xpk[i + 4], q1);
        }
        mu = (s0 + s1) * 0.0625f;
        float var = (q0 + q1) * 0.0625f - mu * mu;
        inv = __builtin_amdgcn_rsqf(var + 1e-5f);

        // rotate 2-deep cmd prefetch
        cmdS = cmdN;
        int tn = t + 3;
        if (tn > T - 1) tn = T - 1;
        if (do_cmd) cmdN = cmd_ptr[(size_t)tn * 4];
    }
#undef GATHER16
}

extern "C" void kernel_launch(void* const* d_in, const int* in_sizes, int n_in,
                              void* d_out, int out_size, void* d_ws, size_t ws_size,
                              hipStream_t stream) {
    const float* init_state = (const float*)d_in[0];
    const float* commands   = (const float*)d_in[1];
    const float* ln_g       = (const float*)d_in[2];
    const float* ln_b       = (const float*)d_in[3];
    const float* W_in       = (const float*)d_in[4];
    const float* b_in       = (const float*)d_in[5];
    const float* W_ih       = (const float*)d_in[6];
    const float* W_hh       = (const float*)d_in[7];
    const float* b_ih       = (const float*)d_in[8];
    const float* b_hh       = (const float*)d_in[9];
    const float* W_out      = (const float*)d_in[10];
    const float* b_out      = (const float*)d_in[11];

    int B = in_sizes[0] / 12;           // 8192
    int T = in_sizes[1] / (B * 4);      // 256

    int blocks = B / 4;                 // 4 batch elements per 64-thread wave
    vm_kernel<<<blocks, 64, 0, stream>>>(init_state, commands, ln_g, ln_b,
                                         W_in, b_in, W_ih, W_hh, b_ih, b_hh,
                                         W_out, b_out, (float*)d_out, B, T);
}